// Round 5
// baseline (997.520 us; speedup 1.0000x reference)
//
#include <hip/hip_runtime.h>
#include <stdint.h>

#define SEQ    32
#define BATCH  64
#define D_IN   37632
#define H1     768
#define H2     100
#define NC     101

#define WOT_LD 104
#define RING   4

// ---- workspace layout, offsets in 4-byte words from ws base ----
#define OFF_WFT   0                                        // [768][768]  WfT[j][k] = Wf_rec[k][j]
#define OFF_WCT   (OFF_WFT + H1*H1)                        // [768][100]
#define OFF_WCRT  (OFF_WCT + H1*H2)                        // [100][100]
#define OFF_WOT   (OFF_WCRT + H2*H2)                       // [100][104]
#define OFF_INF   (((OFF_WOT + H2*WOT_LD) + 63) & ~63)     // [64][768] reduced in_f
#define OFF_ARR   (((OFF_INF + BATCH*H1) + 63) & ~63)      // [64][64] ints
#define OFF_CDN   (OFF_ARR + 64*64)                        // [64][64] ints
#define OFF_ZF    (OFF_CDN + 64*64)                        // [64][RING][32] u32 spike ring
#define OFF_PART  (((OFF_ZF + 64*RING*32) + 255) & ~255)   // [ksplit][64][768]

// =============== kernel A: transposes + counter zeroing ===============
__global__ __launch_bounds__(256) void prep_kernel(
    const float* __restrict__ Wf_rec, const float* __restrict__ Wc_in,
    const float* __restrict__ Wc_rec, const float* __restrict__ W_out,
    float* __restrict__ ws)
{
  const int bid = blockIdx.x, t = threadIdx.x;
  if (bid < 144) {
    __shared__ float tile[64][65];
    const int tr = bid / 12, tc = bid % 12;
    for (int i = t; i < 4096; i += 256) {
      const int r = i >> 6, c = i & 63;
      tile[r][c] = Wf_rec[(tr*64 + r)*H1 + (tc*64 + c)];
    }
    __syncthreads();
    float* WfT = ws + OFF_WFT;
    for (int i = t; i < 4096; i += 256) {
      const int c = i >> 6, r = i & 63;
      WfT[(tc*64 + c)*H1 + (tr*64 + r)] = tile[r][c];
    }
  } else if (bid < 160) {
    const int NA = H1*H2;
    const int NB = H2*H2;
    const int NT = NA + NB + H2*NC;
    for (int idx = (bid-144)*256 + t; idx < NT; idx += 16*256) {
      if (idx < NA) {
        const int j = idx / H2, k = idx % H2;
        ws[OFF_WCT + idx] = Wc_in[k*H1 + j];
      } else if (idx < NA + NB) {
        const int q = idx - NA; const int j = q / H2, k = q % H2;
        ws[OFF_WCRT + q] = Wc_rec[k*H2 + j];
      } else {
        const int q = idx - NA - NB; const int j = q / NC, k = q % NC;
        ws[OFF_WOT + j*WOT_LD + k] = W_out[k*H2 + j];
      }
    }
  } else {
    uint32_t* w = (uint32_t*)ws;
    for (int i = t; i < 64*64*2; i += 256) w[OFF_ARR + i] = 0u;
  }
}

// =============== kernel B: in_f = x @ Wf_in^T — LDS-tiled, coalesced ===============
// grid = 6 col-tiles x ksplit K-chunks. BM=64 (all batch), BN=128, BK=64.
// Staging: thread (q=t&15, r0=t>>4) loads float4 at column q*4 of rows r0+16p —
// 16 consecutive lanes read 256B contiguous of one row (coalesced).
// Compute: tc=t&31 -> cols {tc+32b}, tb=t>>5 -> batches {tb+8a}, acc[8][4].
// LDS padded to 68 floats/row (b128 col-strided reads ~4-way, acceptable).
template<int NTILES>
__global__ __launch_bounds__(256, 2) void gemm_inf(
    const float* __restrict__ x, const float* __restrict__ Wf,
    float* __restrict__ ws)
{
  const int kt = blockIdx.x % 6;
  const int kc = blockIdx.x / 6;
  const int t  = threadIdx.x;
  const int kch = NTILES * 64;
  const int j0  = kc * kch;

  __shared__ float sW[128][68];
  __shared__ float sX[64][68];

  const int q  = t & 15;
  const int r0 = t >> 4;
  const int tc = t & 31;
  const int tb = t >> 5;

  float acc[8][4];
  #pragma unroll
  for (int a = 0; a < 8; ++a)
    #pragma unroll
    for (int b = 0; b < 4; ++b) acc[a][b] = 0.f;

  const float* wbase = Wf + (size_t)(kt*128)*D_IN + j0 + q*4;
  const float* xbase = x  + j0 + q*4;

  float4 gw[2][8], gx[2][4];
  #pragma unroll
  for (int p = 0; p < 8; ++p) gw[0][p] = *(const float4*)(wbase + (size_t)(r0 + 16*p)*D_IN);
  #pragma unroll
  for (int p = 0; p < 4; ++p) gx[0][p] = *(const float4*)(xbase + (size_t)(r0 + 16*p)*D_IN);

  #pragma unroll
  for (int tile = 0; tile < NTILES; ++tile) {
    __syncthreads();   // previous compute done -> LDS reusable
    #pragma unroll
    for (int p = 0; p < 8; ++p) *(float4*)&sW[r0 + 16*p][q*4] = gw[tile & 1][p];
    #pragma unroll
    for (int p = 0; p < 4; ++p) *(float4*)&sX[r0 + 16*p][q*4] = gx[tile & 1][p];
    __syncthreads();
    if (tile + 1 < NTILES) {   // prefetch next tile while computing this one
      const int co = (tile + 1)*64;
      #pragma unroll
      for (int p = 0; p < 8; ++p) gw[(tile+1) & 1][p] = *(const float4*)(wbase + (size_t)(r0 + 16*p)*D_IN + co);
      #pragma unroll
      for (int p = 0; p < 4; ++p) gx[(tile+1) & 1][p] = *(const float4*)(xbase + (size_t)(r0 + 16*p)*D_IN + co);
    }
    #pragma unroll
    for (int kk4 = 0; kk4 < 16; ++kk4) {
      float4 wf[4], xf[8];
      #pragma unroll
      for (int b = 0; b < 4; ++b) wf[b] = *(const float4*)&sW[tc + 32*b][kk4*4];
      #pragma unroll
      for (int a = 0; a < 8; ++a) xf[a] = *(const float4*)&sX[tb + 8*a][kk4*4];
      #pragma unroll
      for (int a = 0; a < 8; ++a)
        #pragma unroll
        for (int b = 0; b < 4; ++b) {
          acc[a][b] = fmaf(xf[a].x, wf[b].x, acc[a][b]);
          acc[a][b] = fmaf(xf[a].y, wf[b].y, acc[a][b]);
          acc[a][b] = fmaf(xf[a].z, wf[b].z, acc[a][b]);
          acc[a][b] = fmaf(xf[a].w, wf[b].w, acc[a][b]);
        }
    }
  }

  float* part = ws + OFF_PART + (size_t)kc*(BATCH*H1);
  #pragma unroll
  for (int a = 0; a < 8; ++a)
    #pragma unroll
    for (int b = 0; b < 4; ++b)
      part[(tb + 8*a)*H1 + kt*128 + tc + 32*b] = acc[a][b];   // lanes tc consecutive -> coalesced
}

// =============== kernel B2: deterministic K-split reduction ===============
__global__ __launch_bounds__(256) void reduce_inf(float* __restrict__ ws, int ksplit)
{
  const int idx = blockIdx.x*256 + threadIdx.x;   // < 64*768
  const float* p = ws + OFF_PART + idx;
  float s = 0.f;
  for (int kc = 0; kc < ksplit; ++kc) s += p[(size_t)kc*(BATCH*H1)];
  ws[OFF_INF + idx] = s;
}

// =============== kernel C: the 32-step scan ===============
// RELAXED device-scope atomics only (no acquire/release/threadfence): avoids
// buffer_inv/buffer_wbl2 so WfT stays per-XCD-L2-resident (proven r3: 2.5x).
// Ordering: producers' mask stores are drained by the s_waitcnt vmcnt(0) inside
// __syncthreads() before lane 0 bumps the arrival counter.
__device__ __forceinline__ int atomic_load_rlx(const int* p) {
  return __hip_atomic_load(p, __ATOMIC_RELAXED, __HIP_MEMORY_SCOPE_AGENT);
}

__global__ __launch_bounds__(256) void scan_kernel(
    float* __restrict__ ws, float* __restrict__ out)
{
  const int bid = blockIdx.x, t = threadIdx.x;
  const float* WfT = ws + OFF_WFT;
  uint32_t* ring_all = (uint32_t*)ws + OFF_ZF;
  int* arr_all = (int*)ws + OFF_ARR;
  int* cdn_all = (int*)ws + OFF_CDN;

  __shared__ uint32_t s_zw[24];
  __shared__ int s_pc[24];
  __shared__ int s_list[H1];
  __shared__ int s_n;

  if (bid < 384) {
    // ---- f-layer WG: 128 neurons of one row; 256 threads = 2 j-halves ----
    const int x8 = bid & 7, qq = bid >> 3;
    const int row = (qq / 6)*8 + x8;
    const int s   = qq % 6;
    const int h   = t >> 7;              // which half of the spike list
    const int k   = s*128 + (t & 127);   // neuron column (same for t and t+128)
    uint32_t* ring = ring_all + row*(RING*32);
    int* arr = arr_all + row*64;
    int* cdn = cdn_all + row*64;

    __shared__ float s_part[256];

    float inf = 0.f;
    if (h == 0) inf = ws[OFF_INF + row*H1 + k];
    float vf = 0.f, iff = 0.f;

    for (int step = 0; step < SEQ; ++step) {
      float Sf = 0.f;
      if (step > 0) {
        if (t == 0) {
          while (atomic_load_rlx(arr) < 6*step) {}
          if (step >= RING) { while (atomic_load_rlx(cdn) < step - (RING-1)) {} }
        }
        __syncthreads();
        const uint32_t* slot = ring + ((step-1) & (RING-1))*32;
        if (t < 24) s_zw[t] = __hip_atomic_load(slot + t, __ATOMIC_RELAXED, __HIP_MEMORY_SCOPE_AGENT);
        __syncthreads();
        if (t == 0) {
          int c = 0;
          #pragma unroll
          for (int w = 0; w < 24; ++w) { s_pc[w] = c; c += __popc(s_zw[w]); }
          s_n = c;
        }
        __syncthreads();
        if (t < 24) {
          uint32_t b = s_zw[t]; int pos = s_pc[t]; const int base = t*32;
          while (b) { const int bit = __builtin_ctz(b); s_list[pos++] = base + bit; b &= b - 1u; }
        }
        __syncthreads();
        const int n = s_n;
        const int i0 = h ? (n >> 1) : 0;
        const int i1 = h ? n : (n >> 1);
        const float* bp = WfT + k;
        float sA = 0.f, sB = 0.f;
        int i = i0;
        for (; i + 8 <= i1; i += 8) {
          const int j0 = s_list[i+0], j1 = s_list[i+1], j2 = s_list[i+2], j3 = s_list[i+3];
          const int j4 = s_list[i+4], j5 = s_list[i+5], j6 = s_list[i+6], j7 = s_list[i+7];
          const float w0 = bp[j0*H1], w1 = bp[j1*H1], w2 = bp[j2*H1], w3 = bp[j3*H1];
          const float w4 = bp[j4*H1], w5 = bp[j5*H1], w6 = bp[j6*H1], w7 = bp[j7*H1];
          sA += w0; sB += w1; sA += w2; sB += w3;
          sA += w4; sB += w5; sA += w6; sB += w7;
        }
        for (; i < i1; ++i) sA += bp[s_list[i]*H1];
        s_part[t] = sA + sB;
        __syncthreads();
        if (h == 0) Sf = s_part[t] + s_part[t + 128];
      }
      bool z = false;
      if (h == 0) {
        const float v_dec = vf + 0.1f*(iff - vf);
        z = v_dec > 0.3f;
        vf  = z ? 0.f : v_dec;
        iff = 0.9f*iff + inf;   // i_dec + cur
        iff = iff + Sf;         // + recurrent(z_prev)
      }
      const uint64_t m = __ballot(z);
      if (t < 128 && (t & 63) == 0) {
        uint32_t* slotw = ring + (step & (RING-1))*32 + 4*s + 2*(t >> 6);
        __hip_atomic_store(slotw + 0, (uint32_t)m,         __ATOMIC_RELAXED, __HIP_MEMORY_SCOPE_AGENT);
        __hip_atomic_store(slotw + 1, (uint32_t)(m >> 32), __ATOMIC_RELAXED, __HIP_MEMORY_SCOPE_AGENT);
      }
      __syncthreads();  // drains vmcnt for ALL waves before lane 0 signals
      if (t == 0) __hip_atomic_fetch_add(arr, 1, __ATOMIC_RELAXED, __HIP_MEMORY_SCOPE_AGENT);
    }
  } else {
    // ---- c-layer + output WG (threads >=128 idle through barriers) ----
    const int row = bid - 384;
    uint32_t* ring = ring_all + row*(RING*32);
    int* arr = arr_all + row*64;
    int* cdn = cdn_all + row*64;
    const float* WcT  = ws + OFF_WCT;
    const float* WcRT = ws + OFF_WCRT;
    const float* WoT  = ws + OFF_WOT;

    __shared__ uint32_t s_zcw[4];
    __shared__ int s_zcpc[4];
    __shared__ int s_zclist[H2];
    __shared__ int s_zcn;

    float vc = 0.f, ic = 0.f, vo = 0.f, io = 0.f;
    if (t == 0) s_zcn = 0;
    __syncthreads();

    for (int step = 0; step < SEQ; ++step) {
      if (t == 0) { while (atomic_load_rlx(arr) < 6*(step+1)) {} }
      __syncthreads();
      const uint32_t* slot = ring + (step & (RING-1))*32;
      if (t < 24) s_zw[t] = __hip_atomic_load(slot + t, __ATOMIC_RELAXED, __HIP_MEMORY_SCOPE_AGENT);
      __syncthreads();  // mask loads drained -> safe to free the slot
      if (t == 0) {
        __hip_atomic_store(cdn, step + 1, __ATOMIC_RELAXED, __HIP_MEMORY_SCOPE_AGENT);
        int c = 0;
        #pragma unroll
        for (int w = 0; w < 24; ++w) { s_pc[w] = c; c += __popc(s_zw[w]); }
        s_n = c;
      }
      __syncthreads();
      if (t < 24) {
        uint32_t b = s_zw[t]; int pos = s_pc[t]; const int base = t*32;
        while (b) { const int bit = __builtin_ctz(b); s_list[pos++] = base + bit; b &= b - 1u; }
      }
      __syncthreads();
      const int n = s_n;
      float Sc = 0.f;
      if (t < H2) {
        const int nzc = s_zcn;
        const float* bp = WcRT + t;
        for (int i = 0; i < nzc; ++i) Sc += bp[s_zclist[i]*H2];
      }
      float Sfc = 0.f;
      if (t < H2) {
        const float* bp = WcT + t;
        float sA = 0.f, sB = 0.f;
        int i = 0;
        for (; i + 8 <= n; i += 8) {
          const int j0 = s_list[i+0], j1 = s_list[i+1], j2 = s_list[i+2], j3 = s_list[i+3];
          const int j4 = s_list[i+4], j5 = s_list[i+5], j6 = s_list[i+6], j7 = s_list[i+7];
          const float w0 = bp[j0*H2], w1 = bp[j1*H2], w2 = bp[j2*H2], w3 = bp[j3*H2];
          const float w4 = bp[j4*H2], w5 = bp[j5*H2], w6 = bp[j6*H2], w7 = bp[j7*H2];
          sA += w0; sB += w1; sA += w2; sB += w3;
          sA += w4; sB += w5; sA += w6; sB += w7;
        }
        for (; i < n; ++i) sA += bp[s_list[i]*H2];
        Sfc = sA + sB;
      }
      bool zc = false;
      if (t < H2) {
        const float v_dec = vc + 0.1f*(ic - vc);
        zc = v_dec > 0.3f;
        vc = zc ? 0.f : v_dec;
        ic = 0.9f*ic + Sfc;
        ic = ic + Sc;
      }
      __syncthreads();        // everyone done reading old s_zclist
      const uint64_t m = __ballot(zc);
      if (t < 128 && (t & 63) == 0) {
        s_zcw[2*(t>>6)+0] = (uint32_t)m;
        s_zcw[2*(t>>6)+1] = (uint32_t)(m >> 32);
      }
      __syncthreads();
      if (t == 0) {
        int c = 0;
        #pragma unroll
        for (int w = 0; w < 4; ++w) { s_zcpc[w] = c; c += __popc(s_zcw[w]); }
        s_zcn = c;
      }
      __syncthreads();
      if (t < 4) {
        uint32_t b = s_zcw[t]; int pos = s_zcpc[t]; const int base = t*32;
        while (b) { const int bit = __builtin_ctz(b); s_zclist[pos++] = base + bit; b &= b - 1u; }
      }
      __syncthreads();
      if (t < NC) {
        float So = 0.f;
        const float* bp = WoT + t;
        const int nzc = s_zcn;
        for (int i = 0; i < nzc; ++i) So += bp[s_zclist[i]*WOT_LD];
        vo = vo + 0.1f*(io - vo);   // uses OLD io
        io = 0.8f*io + So;
        out[((size_t)step*BATCH + row)*NC + t] = vo;
      }
    }
  }
}

extern "C" void kernel_launch(void* const* d_in, const int* in_sizes, int n_in,
                              void* d_out, int out_size, void* d_ws, size_t ws_size,
                              hipStream_t stream) {
  (void)in_sizes; (void)n_in; (void)out_size;
  const float* x      = (const float*)d_in[0];
  const float* Wf_in  = (const float*)d_in[1];
  const float* Wf_rec = (const float*)d_in[2];
  const float* Wc_in  = (const float*)d_in[3];
  const float* Wc_rec = (const float*)d_in[4];
  const float* W_out  = (const float*)d_in[5];
  float* out = (float*)d_out;
  float* ws  = (float*)d_ws;

  // pick K-split by available scratch (98 needs ~22.3 MB, 49 needs ~12.8 MB)
  const size_t need98 = ((size_t)OFF_PART + (size_t)98*BATCH*H1) * 4u;
  const int ksplit = (ws_size >= need98) ? 98 : 49;

  prep_kernel<<<dim3(161), dim3(256), 0, stream>>>(Wf_rec, Wc_in, Wc_rec, W_out, ws);
  if (ksplit == 98) gemm_inf<6> <<<dim3(6*98), dim3(256), 0, stream>>>(x, Wf_in, ws);
  else              gemm_inf<12><<<dim3(6*49), dim3(256), 0, stream>>>(x, Wf_in, ws);
  reduce_inf<<<dim3(BATCH*H1/256), dim3(256), 0, stream>>>(ws, ksplit);
  scan_kernel<<<dim3(448), dim3(256), 0, stream>>>(ws, out);
}

// Round 6
// 614.081 us; speedup vs baseline: 1.6244x; 1.6244x over previous
//
#include <hip/hip_runtime.h>
#include <stdint.h>

#define SEQ    32
#define BATCH  64
#define D_IN   37632
#define H1     768
#define H2     100
#define NC     101

#define WOT_LD 104
#define RING   4

// ---- workspace layout, offsets in 4-byte words from ws base ----
#define OFF_WFT   0                                        // [768][768]  WfT[j][k] = Wf_rec[k][j]
#define OFF_WCT   (OFF_WFT + H1*H1)                        // [768][100]
#define OFF_WCRT  (OFF_WCT + H1*H2)                        // [100][100]
#define OFF_WOT   (OFF_WCRT + H2*H2)                       // [100][104]
#define OFF_INF   (((OFF_WOT + H2*WOT_LD) + 63) & ~63)     // [64][768] reduced in_f
#define OFF_ARR   (((OFF_INF + BATCH*H1) + 63) & ~63)      // [64][64] ints
#define OFF_CDN   (OFF_ARR + 64*64)                        // [64][64] ints
#define OFF_ZF    (OFF_CDN + 64*64)                        // [64][RING][32] u32 spike ring
#define OFF_PART  (((OFF_ZF + 64*RING*32) + 255) & ~255)   // [ksplit][64][768]

// =============== kernel A: transposes + counter zeroing ===============
__global__ __launch_bounds__(256) void prep_kernel(
    const float* __restrict__ Wf_rec, const float* __restrict__ Wc_in,
    const float* __restrict__ Wc_rec, const float* __restrict__ W_out,
    float* __restrict__ ws)
{
  const int bid = blockIdx.x, t = threadIdx.x;
  if (bid < 144) {
    __shared__ float tile[64][65];
    const int tr = bid / 12, tc = bid % 12;
    for (int i = t; i < 4096; i += 256) {
      const int r = i >> 6, c = i & 63;
      tile[r][c] = Wf_rec[(tr*64 + r)*H1 + (tc*64 + c)];
    }
    __syncthreads();
    float* WfT = ws + OFF_WFT;
    for (int i = t; i < 4096; i += 256) {
      const int c = i >> 6, r = i & 63;
      WfT[(tc*64 + c)*H1 + (tr*64 + r)] = tile[r][c];
    }
  } else if (bid < 160) {
    const int NA = H1*H2;
    const int NB = H2*H2;
    const int NT = NA + NB + H2*NC;
    for (int idx = (bid-144)*256 + t; idx < NT; idx += 16*256) {
      if (idx < NA) {
        const int j = idx / H2, k = idx % H2;
        ws[OFF_WCT + idx] = Wc_in[k*H1 + j];
      } else if (idx < NA + NB) {
        const int q = idx - NA; const int j = q / H2, k = q % H2;
        ws[OFF_WCRT + q] = Wc_rec[k*H2 + j];
      } else {
        const int q = idx - NA - NB; const int j = q / NC, k = q % NC;
        ws[OFF_WOT + j*WOT_LD + k] = W_out[k*H2 + j];
      }
    }
  } else {
    uint32_t* w = (uint32_t*)ws;
    for (int i = t; i < 64*64*2; i += 256) w[OFF_ARR + i] = 0u;
  }
}

// =============== kernel B: in_f = x @ Wf_in^T — LDS-tiled, coalesced, NO SPILL ===============
// grid = 6 col-tiles x ksplit K-chunks. BM=64, BN=128, BK=32.
// Staging regs: 6 float4 (24 VGPR), issued BEFORE the barrier (latency hides
// under previous tile's compute). acc[8][4]=32 VGPR. Total ~100 VGPR -> no spill
// (r5 post-mortem: gw[2][8]+gx[2][4]=96 VGPR double-buffer spilled -> 633 MB
// scratch writes).
// Coalescing: 8 consecutive lanes load 128 B contiguous of one row.
template<int NTILES>
__global__ __launch_bounds__(256) void gemm_inf(
    const float* __restrict__ x, const float* __restrict__ Wf,
    float* __restrict__ ws)
{
  const int kt = blockIdx.x % 6;
  const int kc = blockIdx.x / 6;
  const int t  = threadIdx.x;
  const int j0 = kc * (NTILES*32);

  __shared__ float sW[128][36];
  __shared__ float sX[64][36];

  const int q  = t & 7;        // col group: floats q*4..q*4+3 of the 32-wide K tile
  const int r  = t >> 3;       // row base 0..31
  const int tc = t & 31;
  const int tb = t >> 5;

  float acc[8][4];
  #pragma unroll
  for (int a = 0; a < 8; ++a)
    #pragma unroll
    for (int b = 0; b < 4; ++b) acc[a][b] = 0.f;

  const float* wbase = Wf + (size_t)(kt*128)*D_IN + j0 + q*4;
  const float* xbase = x  + j0 + q*4;

  for (int tile = 0; tile < NTILES; ++tile) {
    const int co = tile*32;
    float4 gw0 = *(const float4*)(wbase + (size_t)(r +  0)*D_IN + co);
    float4 gw1 = *(const float4*)(wbase + (size_t)(r + 32)*D_IN + co);
    float4 gw2 = *(const float4*)(wbase + (size_t)(r + 64)*D_IN + co);
    float4 gw3 = *(const float4*)(wbase + (size_t)(r + 96)*D_IN + co);
    float4 gx0 = *(const float4*)(xbase + (size_t)(r +  0)*D_IN + co);
    float4 gx1 = *(const float4*)(xbase + (size_t)(r + 32)*D_IN + co);
    __syncthreads();           // previous tile's compute done -> LDS reusable
    *(float4*)&sW[r +  0][q*4] = gw0;
    *(float4*)&sW[r + 32][q*4] = gw1;
    *(float4*)&sW[r + 64][q*4] = gw2;
    *(float4*)&sW[r + 96][q*4] = gw3;
    *(float4*)&sX[r +  0][q*4] = gx0;
    *(float4*)&sX[r + 32][q*4] = gx1;
    __syncthreads();
    #pragma unroll
    for (int kk = 0; kk < 8; ++kk) {
      float4 wf[4], xf[8];
      #pragma unroll
      for (int b = 0; b < 4; ++b) wf[b] = *(const float4*)&sW[tc + 32*b][kk*4];
      #pragma unroll
      for (int a = 0; a < 8; ++a) xf[a] = *(const float4*)&sX[tb + 8*a][kk*4];
      #pragma unroll
      for (int a = 0; a < 8; ++a)
        #pragma unroll
        for (int b = 0; b < 4; ++b) {
          acc[a][b] = fmaf(xf[a].x, wf[b].x, acc[a][b]);
          acc[a][b] = fmaf(xf[a].y, wf[b].y, acc[a][b]);
          acc[a][b] = fmaf(xf[a].z, wf[b].z, acc[a][b]);
          acc[a][b] = fmaf(xf[a].w, wf[b].w, acc[a][b]);
        }
    }
  }

  float* part = ws + OFF_PART + (size_t)kc*(BATCH*H1);
  #pragma unroll
  for (int a = 0; a < 8; ++a)
    #pragma unroll
    for (int b = 0; b < 4; ++b)
      part[(tb + 8*a)*H1 + kt*128 + tc + 32*b] = acc[a][b];   // lanes tc consecutive -> coalesced
}

// =============== kernel B2: deterministic K-split reduction ===============
__global__ __launch_bounds__(256) void reduce_inf(float* __restrict__ ws, int ksplit)
{
  const int idx = blockIdx.x*256 + threadIdx.x;   // < 64*768
  const float* p = ws + OFF_PART + idx;
  float s = 0.f;
  for (int kc = 0; kc < ksplit; ++kc) s += p[(size_t)kc*(BATCH*H1)];
  ws[OFF_INF + idx] = s;
}

// =============== kernel C: the 32-step scan (r3-proven 128-thread form) ===============
// RELAXED device-scope atomics only (no acquire/release/threadfence): avoids
// buffer_inv/buffer_wbl2 so WfT stays per-XCD-L2-resident (proven r3: 2.5x).
// Ordering: producers' mask stores are drained by the s_waitcnt vmcnt(0) inside
// __syncthreads() before lane 0 bumps the arrival counter.
__device__ __forceinline__ int atomic_load_rlx(const int* p) {
  return __hip_atomic_load(p, __ATOMIC_RELAXED, __HIP_MEMORY_SCOPE_AGENT);
}

__global__ __launch_bounds__(128) void scan_kernel(
    float* __restrict__ ws, float* __restrict__ out)
{
  const int bid = blockIdx.x, t = threadIdx.x;
  const float* WfT = ws + OFF_WFT;
  uint32_t* ring_all = (uint32_t*)ws + OFF_ZF;
  int* arr_all = (int*)ws + OFF_ARR;
  int* cdn_all = (int*)ws + OFF_CDN;

  __shared__ uint32_t s_zw[24];
  __shared__ int s_pc[24];
  __shared__ int s_list[H1];
  __shared__ int s_n;

  if (bid < 384) {
    // ---- f-layer WG: one of 6 slices (128 neurons) of one batch row ----
    const int x8 = bid & 7, qq = bid >> 3;
    const int row = (qq / 6)*8 + x8;
    const int s   = qq % 6;
    const int k   = s*128 + t;            // this thread's neuron
    uint32_t* ring = ring_all + row*(RING*32);
    int* arr = arr_all + row*64;
    int* cdn = cdn_all + row*64;

    float inf = ws[OFF_INF + row*H1 + k];
    float vf = 0.f, iff = 0.f;

    for (int step = 0; step < SEQ; ++step) {
      float Sf = 0.f;
      if (step > 0) {
        if (t == 0) {
          while (atomic_load_rlx(arr) < 6*step) {}
          if (step >= RING) { while (atomic_load_rlx(cdn) < step - (RING-1)) {} }
        }
        __syncthreads();
        const uint32_t* slot = ring + ((step-1) & (RING-1))*32;
        if (t < 24) s_zw[t] = __hip_atomic_load(slot + t, __ATOMIC_RELAXED, __HIP_MEMORY_SCOPE_AGENT);
        __syncthreads();
        if (t == 0) {
          int c = 0;
          #pragma unroll
          for (int w = 0; w < 24; ++w) { s_pc[w] = c; c += __popc(s_zw[w]); }
          s_n = c;
        }
        __syncthreads();
        if (t < 24) {
          uint32_t b = s_zw[t]; int pos = s_pc[t]; const int base = t*32;
          while (b) { const int bit = __builtin_ctz(b); s_list[pos++] = base + bit; b &= b - 1u; }
        }
        __syncthreads();
        const int n = s_n;
        const float* bp = WfT + k;
        float sA = 0.f, sB = 0.f;
        int i = 0;
        for (; i + 8 <= n; i += 8) {
          const int j0 = s_list[i+0], j1 = s_list[i+1], j2 = s_list[i+2], j3 = s_list[i+3];
          const int j4 = s_list[i+4], j5 = s_list[i+5], j6 = s_list[i+6], j7 = s_list[i+7];
          const float w0 = bp[j0*H1], w1 = bp[j1*H1], w2 = bp[j2*H1], w3 = bp[j3*H1];
          const float w4 = bp[j4*H1], w5 = bp[j5*H1], w6 = bp[j6*H1], w7 = bp[j7*H1];
          sA += w0; sB += w1; sA += w2; sB += w3;
          sA += w4; sB += w5; sA += w6; sB += w7;
        }
        for (; i < n; ++i) sA += bp[s_list[i]*H1];
        Sf = sA + sB;
      }
      // LIF update (mirrors reference op order)
      const float v_dec = vf + 0.1f*(iff - vf);
      const bool z = v_dec > 0.3f;
      vf  = z ? 0.f : v_dec;
      iff = 0.9f*iff + inf;   // i_dec + cur
      iff = iff + Sf;         // + recurrent(z_prev)
      // publish zf(step) slice
      const uint64_t m = __ballot(z);
      uint32_t* slotw = ring + (step & (RING-1))*32 + 4*s + 2*(t >> 6);
      if ((t & 63) == 0) {
        __hip_atomic_store(slotw + 0, (uint32_t)m,         __ATOMIC_RELAXED, __HIP_MEMORY_SCOPE_AGENT);
        __hip_atomic_store(slotw + 1, (uint32_t)(m >> 32), __ATOMIC_RELAXED, __HIP_MEMORY_SCOPE_AGENT);
      }
      __syncthreads();  // drains vmcnt for ALL waves before lane 0 signals
      if (t == 0) __hip_atomic_fetch_add(arr, 1, __ATOMIC_RELAXED, __HIP_MEMORY_SCOPE_AGENT);
    }
  } else {
    // ---- c-layer + output WG: whole 100-neuron LIF + 101-wide LI for one row ----
    const int row = bid - 384;
    uint32_t* ring = ring_all + row*(RING*32);
    int* arr = arr_all + row*64;
    int* cdn = cdn_all + row*64;
    const float* WcT  = ws + OFF_WCT;
    const float* WcRT = ws + OFF_WCRT;
    const float* WoT  = ws + OFF_WOT;

    __shared__ uint32_t s_zcw[4];
    __shared__ int s_zcpc[4];
    __shared__ int s_zclist[H2];
    __shared__ int s_zcn;

    float vc = 0.f, ic = 0.f, vo = 0.f, io = 0.f;
    if (t == 0) s_zcn = 0;
    __syncthreads();

    for (int step = 0; step < SEQ; ++step) {
      if (t == 0) { while (atomic_load_rlx(arr) < 6*(step+1)) {} }
      __syncthreads();
      const uint32_t* slot = ring + (step & (RING-1))*32;
      if (t < 24) s_zw[t] = __hip_atomic_load(slot + t, __ATOMIC_RELAXED, __HIP_MEMORY_SCOPE_AGENT);
      __syncthreads();  // mask loads drained -> safe to free the slot
      if (t == 0) {
        __hip_atomic_store(cdn, step + 1, __ATOMIC_RELAXED, __HIP_MEMORY_SCOPE_AGENT);
        int c = 0;
        #pragma unroll
        for (int w = 0; w < 24; ++w) { s_pc[w] = c; c += __popc(s_zw[w]); }
        s_n = c;
      }
      __syncthreads();
      if (t < 24) {
        uint32_t b = s_zw[t]; int pos = s_pc[t]; const int base = t*32;
        while (b) { const int bit = __builtin_ctz(b); s_list[pos++] = base + bit; b &= b - 1u; }
      }
      __syncthreads();
      const int n = s_n;
      float Sc = 0.f;
      if (t < H2) {
        const int nzc = s_zcn;
        const float* bp = WcRT + t;
        for (int i = 0; i < nzc; ++i) Sc += bp[s_zclist[i]*H2];
      }
      float Sfc = 0.f;
      if (t < H2) {
        const float* bp = WcT + t;
        float sA = 0.f, sB = 0.f;
        int i = 0;
        for (; i + 8 <= n; i += 8) {
          const int j0 = s_list[i+0], j1 = s_list[i+1], j2 = s_list[i+2], j3 = s_list[i+3];
          const int j4 = s_list[i+4], j5 = s_list[i+5], j6 = s_list[i+6], j7 = s_list[i+7];
          const float w0 = bp[j0*H2], w1 = bp[j1*H2], w2 = bp[j2*H2], w3 = bp[j3*H2];
          const float w4 = bp[j4*H2], w5 = bp[j5*H2], w6 = bp[j6*H2], w7 = bp[j7*H2];
          sA += w0; sB += w1; sA += w2; sB += w3;
          sA += w4; sB += w5; sA += w6; sB += w7;
        }
        for (; i < n; ++i) sA += bp[s_list[i]*H2];
        Sfc = sA + sB;
      }
      bool zc = false;
      if (t < H2) {
        const float v_dec = vc + 0.1f*(ic - vc);
        zc = v_dec > 0.3f;
        vc = zc ? 0.f : v_dec;
        ic = 0.9f*ic + Sfc;
        ic = ic + Sc;
      }
      __syncthreads();        // everyone done reading old s_zclist
      const uint64_t m = __ballot(zc);
      if ((t & 63) == 0) {
        s_zcw[2*(t>>6)+0] = (uint32_t)m;
        s_zcw[2*(t>>6)+1] = (uint32_t)(m >> 32);
      }
      __syncthreads();
      if (t == 0) {
        int c = 0;
        #pragma unroll
        for (int w = 0; w < 4; ++w) { s_zcpc[w] = c; c += __popc(s_zcw[w]); }
        s_zcn = c;
      }
      __syncthreads();
      if (t < 4) {
        uint32_t b = s_zcw[t]; int pos = s_zcpc[t]; const int base = t*32;
        while (b) { const int bit = __builtin_ctz(b); s_zclist[pos++] = base + bit; b &= b - 1u; }
      }
      __syncthreads();
      if (t < NC) {
        float So = 0.f;
        const float* bp = WoT + t;
        const int nzc = s_zcn;
        for (int i = 0; i < nzc; ++i) So += bp[s_zclist[i]*WOT_LD];
        vo = vo + 0.1f*(io - vo);   // uses OLD io
        io = 0.8f*io + So;
        out[((size_t)step*BATCH + row)*NC + t] = vo;
      }
    }
  }
}

extern "C" void kernel_launch(void* const* d_in, const int* in_sizes, int n_in,
                              void* d_out, int out_size, void* d_ws, size_t ws_size,
                              hipStream_t stream) {
  (void)in_sizes; (void)n_in; (void)out_size;
  const float* x      = (const float*)d_in[0];
  const float* Wf_in  = (const float*)d_in[1];
  const float* Wf_rec = (const float*)d_in[2];
  const float* Wc_in  = (const float*)d_in[3];
  const float* Wc_rec = (const float*)d_in[4];
  const float* W_out  = (const float*)d_in[5];
  float* out = (float*)d_out;
  float* ws  = (float*)d_ws;

  // pick K-split by available scratch (98 needs ~23 MB, 49 needs ~13 MB)
  const size_t need98 = ((size_t)OFF_PART + (size_t)98*BATCH*H1) * 4u;
  const int ksplit = (ws_size >= need98) ? 98 : 49;

  prep_kernel<<<dim3(161), dim3(256), 0, stream>>>(Wf_rec, Wc_in, Wc_rec, W_out, ws);
  if (ksplit == 98) gemm_inf<12><<<dim3(6*98), dim3(256), 0, stream>>>(x, Wf_in, ws);
  else              gemm_inf<24><<<dim3(6*49), dim3(256), 0, stream>>>(x, Wf_in, ws);
  reduce_inf<<<dim3(BATCH*H1/256), dim3(256), 0, stream>>>(ws, ksplit);
  scan_kernel<<<dim3(448), dim3(128), 0, stream>>>(ws, out);
}